// Round 3
// baseline (1626.329 us; speedup 1.0000x reference)
//
#include <hip/hip_runtime.h>
#include <hip/hip_bf16.h>
#include <math.h>

// ---------------- constants for this problem ----------------
#define DIM 256       // graph-layer width
#define EMB 64
#define HID1 1024
#define HID2 512
#define EPSBN 1e-5f

typedef float f32x4 __attribute__((ext_vector_type(4)));
typedef __bf16 bf16x8 __attribute__((ext_vector_type(8)));

// ---------------- bf16 split helpers ----------------
__device__ __forceinline__ unsigned short f2bf(float f) {
    unsigned u = __float_as_uint(f);
    unsigned r = (u + 0x7fffu + ((u >> 16) & 1u)) >> 16;
    return (unsigned short)r;
}
__device__ __forceinline__ float bf2f(unsigned short h) {
    return __uint_as_float(((unsigned)h) << 16);
}

// ---------------- small utility kernels ----------------

__global__ __launch_bounds__(128) void k_embed(const int* __restrict__ ui, const int* __restrict__ ii,
                                               const float* __restrict__ eu, const float* __restrict__ ei,
                                               float* __restrict__ x0) {
    int i = blockIdx.x, t = threadIdx.x;
    float v = (t < 64) ? eu[(size_t)ui[i] * 64 + t] : ei[(size_t)ii[i] * 64 + (t - 64)];
    x0[(size_t)i * 128 + t] = v;
}

__global__ __launch_bounds__(256) void k_hist(const int* __restrict__ dst, int* __restrict__ cnt, int E) {
    int e = blockIdx.x * 256 + threadIdx.x;
    if (e < E) atomicAdd(&cnt[dst[e]], 1);
}

// exclusive scan of 4096 ints (single block, 1024 threads x 4)
__global__ __launch_bounds__(1024) void k_scan4096(const int* __restrict__ cnt, int* __restrict__ roff) {
    __shared__ int s[1024];
    int t = threadIdx.x;
    int v0 = cnt[4*t], v1 = cnt[4*t+1], v2 = cnt[4*t+2], v3 = cnt[4*t+3];
    int loc = v0 + v1 + v2 + v3;
    s[t] = loc;
    for (int o = 1; o < 1024; o <<= 1) {
        __syncthreads();
        int x = (t >= o) ? s[t - o] : 0;
        __syncthreads();
        s[t] += x;
    }
    __syncthreads();
    int excl = s[t] - loc;
    roff[4*t]   = excl;
    roff[4*t+1] = excl + v0;
    roff[4*t+2] = excl + v0 + v1;
    roff[4*t+3] = excl + v0 + v1 + v2;
    if (t == 1023) roff[4096] = s[1023];
}

__global__ __launch_bounds__(256) void k_csr_fill(const int* __restrict__ src, const int* __restrict__ dst,
                                                  const int* __restrict__ roff, int* __restrict__ cursor,
                                                  int* __restrict__ csrc, int E) {
    int e = blockIdx.x * 256 + threadIdx.x;
    if (e < E) {
        int d = dst[e];
        int pos = roff[d] + atomicAdd(&cursor[d], 1);
        csrc[pos] = src[e];
    }
}

__global__ __launch_bounds__(256) void k_coefs(const int* __restrict__ cnt, float* __restrict__ dinv,
                                               float* __restrict__ dinvc, float* __restrict__ invc, int n) {
    int i = blockIdx.x * 256 + threadIdx.x;
    if (i < n) {
        int c = cnt[i];
        dinv[i]  = rsqrtf((float)c + 1.0f);
        dinvc[i] = (c > 0) ? rsqrtf((float)c) : 0.0f;
        invc[i]  = 1.0f / (float)(c > 0 ? c : 1);
    }
}

// ---------------- fp32 tiled GEMM: C[M,N] = A[M,K] @ B[K,N] ----------------
// 64x64 block tile, 4x4 per thread, BK=32. M%64==0, K%32==0 assumed. N guarded.
template<int BIAS, int RELU, int ACC>
__global__ __launch_bounds__(256) void gemm64(const float* __restrict__ A, const float* __restrict__ B,
                                              const float* __restrict__ bias, float* __restrict__ C,
                                              int M, int K, int N) {
    __shared__ float As[32][68];   // [k][m]
    __shared__ float Bs[32][68];   // [k][n]
    const int bn = blockIdx.x * 64, bm = blockIdx.y * 64;
    const int tid = threadIdx.x;
    const int tx = tid & 15, ty = tid >> 4;
    const int alm = tid >> 2;           // 0..63  A row within tile
    const int alk = (tid & 3) * 8;      // 0,8,16,24
    const int blk = tid >> 3;           // 0..31 B row (k)
    const int bln = (tid & 7) * 8;      // 0..56
    const bool nfull = (bn + 64 <= N);

    float acc[4][4] = {};

    for (int k0 = 0; k0 < K; k0 += 32) {
        const float* ap = A + (size_t)(bm + alm) * K + k0 + alk;
        float4 a0 = *(const float4*)ap;
        float4 a1 = *(const float4*)(ap + 4);
        As[alk+0][alm] = a0.x; As[alk+1][alm] = a0.y; As[alk+2][alm] = a0.z; As[alk+3][alm] = a0.w;
        As[alk+4][alm] = a1.x; As[alk+5][alm] = a1.y; As[alk+6][alm] = a1.z; As[alk+7][alm] = a1.w;

        const float* bp = B + (size_t)(k0 + blk) * N + bn + bln;
        if (nfull) {
            *(float4*)&Bs[blk][bln]     = *(const float4*)bp;
            *(float4*)&Bs[blk][bln + 4] = *(const float4*)(bp + 4);
        } else {
            #pragma unroll
            for (int j = 0; j < 8; ++j)
                Bs[blk][bln + j] = (bn + bln + j < N) ? bp[j] : 0.0f;
        }
        __syncthreads();
        #pragma unroll
        for (int k = 0; k < 32; ++k) {
            float4 av = *(const float4*)&As[k][ty * 4];
            float4 bv = *(const float4*)&Bs[k][tx * 4];
            float a[4] = {av.x, av.y, av.z, av.w};
            float b[4] = {bv.x, bv.y, bv.z, bv.w};
            #pragma unroll
            for (int i = 0; i < 4; ++i)
                #pragma unroll
                for (int j = 0; j < 4; ++j)
                    acc[i][j] = fmaf(a[i], b[j], acc[i][j]);
        }
        __syncthreads();
    }

    const int row = bm + ty * 4, col = bn + tx * 4;
    #pragma unroll
    for (int i = 0; i < 4; ++i) {
        float* cp = C + (size_t)(row + i) * N + col;
        #pragma unroll
        for (int j = 0; j < 4; ++j) {
            if (col + j < N) {
                float v = acc[i][j];
                if (ACC)  v += cp[j];
                if (BIAS) v += bias[col + j];
                if (RELU) v = fmaxf(v, 0.0f);
                cp[j] = v;
            }
        }
    }
}

// ---------------- split-bf16 conversion kernels ----------------

// X [total] f32 -> Ah, Al bf16 (hi + residual)
__global__ __launch_bounds__(256) void k_convA(const float* __restrict__ X, unsigned short* __restrict__ Ah,
                                               unsigned short* __restrict__ Al, int total) {
    int i = blockIdx.x * 256 + threadIdx.x;
    if (i < total) {
        float f = X[i];
        unsigned short h = f2bf(f);
        Ah[i] = h;
        Al[i] = f2bf(f - bf2f(h));
    }
}

// W [K=256][NC] f32 row-major  ->  Bh, Bl [NPAD][256] bf16 (transposed + split), pad rows zeroed.
// grid (NPAD/64, K/64), 256 threads; tile 64k x 64n via LDS.
__global__ __launch_bounds__(256) void k_convB(const float* __restrict__ W, unsigned short* __restrict__ Bh,
                                               unsigned short* __restrict__ Bl, int K, int NC) {
    __shared__ float tile[64][65];
    const int n0 = blockIdx.x * 64, k0 = blockIdx.y * 64;
    const int t = threadIdx.x;
    const int tn = t & 63, tk4 = t >> 6;
    for (int kk = tk4; kk < 64; kk += 4) {
        int n = n0 + tn;
        tile[kk][tn] = (n < NC) ? W[(size_t)(k0 + kk) * NC + n] : 0.0f;
    }
    __syncthreads();
    const int wn = t >> 2, wk = (t & 3) * 16;
    size_t base = (size_t)(n0 + wn) * K + k0 + wk;
    #pragma unroll
    for (int j = 0; j < 16; ++j) {
        float f = tile[wk + j][wn];
        unsigned short h = f2bf(f);
        Bh[base + j] = h;
        Bl[base + j] = f2bf(f - bf2f(h));
    }
}

// ---------------- split-bf16 MFMA prediction GEMM ----------------
// C[4096, NC] = (Ah+Al)[4096,256] @ (Bh+Bl)^T_state + bias, via Ah*Bh + Ah*Bl + Al*Bh.
// A*: [4096][256] bf16 row-major. B*: [NPAD][256] bf16 (n-major, pre-transposed).
// 128x128 tile, 4 waves (2x2), BK=64, 16x16x32 bf16 MFMA, m97 2-barrier structure.
// LDS XOR swizzle (slot ^= row&7) applied on the GLOBAL source of global_load_lds
// and on the ds_read side (rule #21: linear LDS dest, same involution both sides).
__global__ __launch_bounds__(256) void gemm_pred_mfma(
    const unsigned short* __restrict__ Ah, const unsigned short* __restrict__ Al,
    const unsigned short* __restrict__ Bh, const unsigned short* __restrict__ Bl,
    const float* __restrict__ bias, float* __restrict__ C, int NC) {
    __shared__ bf16x8 smem[2048];                 // 32 KB: As [0,16K), Bs [16K,32K)
    char* AsB = (char*)smem;
    char* BsB = (char*)smem + 16384;
    const int tid = threadIdx.x;
    const int w = tid >> 6, l = tid & 63;
    const int wr = w >> 1, wc = w & 1;            // wave 64x64 sub-tile
    const int g = l >> 4, lr = l & 15;
    const int bm = blockIdx.y * 128, bn = blockIdx.x * 128;

    f32x4 acc[4][4] = {};

    for (int t = 0; t < 12; ++t) {                // 3 terms x 4 K-steps of 64
        const int kk = (t & 3) * 64;
        const unsigned short* Ag = (t < 8) ? Ah : Al;              // t<8: Ah, else Al
        const unsigned short* Bg = (t >= 4 && t < 8) ? Bl : Bh;    // t in [4,8): Bl
        // stage: each wave fills 32 rows of As and Bs (8 rows / 1KB per call)
        #pragma unroll
        for (int c = 0; c < 4; ++c) {
            const int row = w * 32 + c * 8 + (l >> 3);   // tile-local row
            const int q = l & 7;                         // linear LDS slot this lane fills
            const int gs = q ^ (row & 7);                // pre-swizzled global slot
            const unsigned short* ga = Ag + (size_t)(bm + row) * 256 + kk + gs * 8;
            const unsigned short* gb = Bg + (size_t)(bn + row) * 256 + kk + gs * 8;
            __builtin_amdgcn_global_load_lds(
                (const __attribute__((address_space(1))) void*)ga,
                (__attribute__((address_space(3))) void*)(AsB + (w * 32 + c * 8) * 128), 16, 0, 0);
            __builtin_amdgcn_global_load_lds(
                (const __attribute__((address_space(1))) void*)gb,
                (__attribute__((address_space(3))) void*)(BsB + (w * 32 + c * 8) * 128), 16, 0, 0);
        }
        __syncthreads();
        #pragma unroll
        for (int ks = 0; ks < 2; ++ks) {          // two k-slices of 32
            bf16x8 af[4], bfr[4];
            #pragma unroll
            for (int m = 0; m < 4; ++m) {
                const int row = wr * 64 + m * 16 + lr;
                const int slot = (ks * 4 + g) ^ (row & 7);
                af[m] = *(const bf16x8*)(AsB + row * 128 + slot * 16);
            }
            #pragma unroll
            for (int n = 0; n < 4; ++n) {
                const int row = wc * 64 + n * 16 + lr;
                const int slot = (ks * 4 + g) ^ (row & 7);
                bfr[n] = *(const bf16x8*)(BsB + row * 128 + slot * 16);
            }
            #pragma unroll
            for (int m = 0; m < 4; ++m)
                #pragma unroll
                for (int n = 0; n < 4; ++n)
                    acc[m][n] = __builtin_amdgcn_mfma_f32_16x16x32_bf16(af[m], bfr[n], acc[m][n], 0, 0, 0);
        }
        __syncthreads();
    }
    // epilogue: C/D mapping col=lane&15, row=(lane>>4)*4+reg  [m89-verified]
    #pragma unroll
    for (int n = 0; n < 4; ++n) {
        const int col = bn + wc * 64 + n * 16 + lr;
        if (col < NC) {
            const float bv = bias[col];
            #pragma unroll
            for (int m = 0; m < 4; ++m) {
                const int row0 = bm + wr * 64 + m * 16 + g * 4;
                #pragma unroll
                for (int r = 0; r < 4; ++r)
                    C[(size_t)(row0 + r) * NC + col] = acc[m][n][r] + bv;
            }
        }
    }
}

// ---------------- aggregations (block per node, 256 threads = 256 cols) ----------------

__global__ __launch_bounds__(256) void k_gcn_agg(const float* __restrict__ xw, const int* __restrict__ roff,
                                                 const int* __restrict__ csrc, const float* __restrict__ dinv,
                                                 const float* __restrict__ b, float* __restrict__ out) {
    int i = blockIdx.x, c = threadIdx.x;
    float di = dinv[i];
    float acc = xw[(size_t)i * DIM + c] * di * di;
    int beg = roff[i], end = roff[i + 1];
    for (int j = beg; j < end; ++j) {
        int s = csrc[j];
        acc = fmaf(xw[(size_t)s * DIM + c], dinv[s] * di, acc);
    }
    out[(size_t)i * DIM + c] = acc + b[c];
}

__global__ __launch_bounds__(256) void k_sage_agg(const float* __restrict__ x, const int* __restrict__ roff,
                                                  const int* __restrict__ csrc, const float* __restrict__ invc,
                                                  float* __restrict__ out) {
    int i = blockIdx.x, c = threadIdx.x;
    float acc = 0.0f;
    int beg = roff[i], end = roff[i + 1];
    for (int j = beg; j < end; ++j) acc += x[(size_t)csrc[j] * DIM + c];
    out[(size_t)i * DIM + c] = acc * invc[i];
}

__global__ __launch_bounds__(256) void k_cheb_agg(const float* __restrict__ x, const int* __restrict__ roff,
                                                  const int* __restrict__ csrc, const float* __restrict__ dinvc,
                                                  float* __restrict__ out) {
    int i = blockIdx.x, c = threadIdx.x;
    float dci = dinvc[i];
    float acc = 0.0f;
    int beg = roff[i], end = roff[i + 1];
    for (int j = beg; j < end; ++j) {
        int s = csrc[j];
        acc = fmaf(x[(size_t)s * DIM + c], -(dinvc[s] * dci), acc);
    }
    out[(size_t)i * DIM + c] = acc;
}

// ---------------- BatchNorm (batch stats) ----------------

__global__ __launch_bounds__(256) void k_colstats(const float* __restrict__ X, float* __restrict__ sum,
                                                  float* __restrict__ sq) {
    int c = threadIdx.x;
    int r0 = blockIdx.x * 64;
    float s = 0.0f, q = 0.0f;
    for (int r = r0; r < r0 + 64; ++r) {
        float v = X[(size_t)r * DIM + c];
        s += v;
        q = fmaf(v, v, q);
    }
    atomicAdd(&sum[c], s);
    atomicAdd(&sq[c], q);
}

__global__ __launch_bounds__(256) void k_bnfin(const float* __restrict__ sum, const float* __restrict__ sq,
                                               float* __restrict__ mu, float* __restrict__ rstd, float invn) {
    int c = threadIdx.x;
    float m = sum[c] * invn;
    float var = sq[c] * invn - m * m;
    mu[c] = m;
    rstd[c] = rsqrtf(var + EPSBN);
}

__global__ __launch_bounds__(256) void k_bnapply(const float* __restrict__ X, const float* __restrict__ mu,
                                                 const float* __restrict__ rstd, const float* __restrict__ g,
                                                 const float* __restrict__ bt, float* __restrict__ out) {
    int r = blockIdx.x, c = threadIdx.x;
    size_t idx = (size_t)r * DIM + c;
    float v = (X[idx] - mu[c]) * rstd[c] * g[c] + bt[c];
    out[idx] = fmaxf(v, 0.0f);
}

// ---------------- GAT ----------------

__global__ __launch_bounds__(256) void k_gat_proj(const float* __restrict__ xw, const float* __restrict__ a_s,
                                                  const float* __restrict__ a_d, float* __restrict__ ps,
                                                  float* __restrict__ pd) {
    int i = blockIdx.x, t = threadIdx.x;
    __shared__ float r1[256], r2[256];
    float v = xw[(size_t)i * DIM + t];
    r1[t] = v * a_s[t];
    r2[t] = v * a_d[t];
    __syncthreads();
    for (int o = 128; o > 0; o >>= 1) {
        if (t < o) { r1[t] += r1[t + o]; r2[t] += r2[t + o]; }
        __syncthreads();
    }
    if (t == 0) { ps[i] = r1[0]; pd[i] = r2[0]; }
}

__device__ __forceinline__ float leaky02(float x) { return x > 0.0f ? x : 0.2f * x; }

__global__ __launch_bounds__(256) void k_gat_agg(const float* __restrict__ xw, const float* __restrict__ ps,
                                                 const float* __restrict__ pd, const int* __restrict__ roff,
                                                 const int* __restrict__ csrc, const float* __restrict__ b,
                                                 float* __restrict__ out) {
    int i = blockIdx.x, t = threadIdx.x;
    int beg = roff[i], end = roff[i + 1];
    float ad = pd[i];
    __shared__ float red[256];
    // pass 1: segment max (edges + self loop)
    float lm = -1e30f;
    for (int j = beg + t; j < end; j += 256) lm = fmaxf(lm, leaky02(ps[csrc[j]] + ad));
    if (t == 0) lm = fmaxf(lm, leaky02(ps[i] + ad));
    red[t] = lm; __syncthreads();
    for (int o = 128; o > 0; o >>= 1) { if (t < o) red[t] = fmaxf(red[t], red[t + o]); __syncthreads(); }
    float m = red[0]; __syncthreads();
    // pass 2: sum of exp
    float ls = 0.0f;
    for (int j = beg + t; j < end; j += 256) ls += __expf(leaky02(ps[csrc[j]] + ad) - m);
    if (t == 0) ls += __expf(leaky02(ps[i] + ad) - m);
    red[t] = ls; __syncthreads();
    for (int o = 128; o > 0; o >>= 1) { if (t < o) red[t] += red[t + o]; __syncthreads(); }
    float inv_s = 1.0f / red[0];
    // pass 3: weighted aggregate (t = column)
    float acc = __expf(leaky02(ps[i] + ad) - m) * xw[(size_t)i * DIM + t];
    for (int j = beg; j < end; ++j) {
        int s = csrc[j];
        acc = fmaf(__expf(leaky02(ps[s] + ad) - m), xw[(size_t)s * DIM + t], acc);
    }
    float v = acc * inv_s + b[t];
    out[(size_t)i * DIM + t] = v > 0.0f ? v : expm1f(v);
}

// ---------------- host-side launch ----------------

extern "C" void kernel_launch(void* const* d_in, const int* in_sizes, int n_in,
                              void* d_out, int out_size, void* d_ws, size_t ws_size,
                              hipStream_t stream) {
    const int*   ui  = (const int*)d_in[0];
    const int*   ii  = (const int*)d_in[1];
    const int*   edg = (const int*)d_in[2];
    const float* eu  = (const float*)d_in[3];
    const float* ei  = (const float*)d_in[4];
    const float* w1  = (const float*)d_in[5];  const float* b1  = (const float*)d_in[6];
    const float* w2  = (const float*)d_in[7];  const float* b2  = (const float*)d_in[8];
    const float* gw0 = (const float*)d_in[9];  const float* gb0 = (const float*)d_in[10];
    const float* bg0 = (const float*)d_in[11]; const float* bb0 = (const float*)d_in[12];
    const float* gw1 = (const float*)d_in[13]; const float* gb1 = (const float*)d_in[14];
    const float* bg1 = (const float*)d_in[15]; const float* bb1 = (const float*)d_in[16];
    const float* swl = (const float*)d_in[17]; const float* sbl = (const float*)d_in[18];
    const float* swr = (const float*)d_in[19];
    const float* cw0 = (const float*)d_in[20]; const float* cw1 = (const float*)d_in[21];
    const float* cb  = (const float*)d_in[22];
    const float* aw0 = (const float*)d_in[23]; const float* as0 = (const float*)d_in[24];
    const float* ad0 = (const float*)d_in[25]; const float* ab0 = (const float*)d_in[26];
    const float* aw1 = (const float*)d_in[27]; const float* as1 = (const float*)d_in[28];
    const float* ad1 = (const float*)d_in[29]; const float* ab1 = (const float*)d_in[30];
    const float* pw  = (const float*)d_in[31]; const float* pb  = (const float*)d_in[32];
    float* out = (float*)d_out;

    const int N  = in_sizes[0];          // 4096
    const int E  = in_sizes[2] / 2;      // 131072
    const int NC = in_sizes[32];         // 41476
    const int NPAD = ((NC + 127) / 128) * 128;   // 41600
    const int* src = edg;
    const int* dst = edg + E;

    // workspace carve (256B aligned chunks)
    char* p = (char*)d_ws;
    auto alloc = [&](size_t bytes) -> void* {
        void* r = (void*)p;
        p += ((bytes + 255) / 256) * 256;
        return r;
    };
    float* x0   = (float*)alloc((size_t)N * 128 * 4);
    float* h1   = (float*)alloc((size_t)N * HID1 * 4);
    float* h2   = (float*)alloc((size_t)N * HID2 * 4);
    float* xa   = (float*)alloc((size_t)N * DIM * 4);
    float* xb   = (float*)alloc((size_t)N * DIM * 4);
    float* xc   = (float*)alloc((size_t)N * DIM * 4);
    float* xd   = (float*)alloc((size_t)N * DIM * 4);
    float* dinv = (float*)alloc(N * 4);
    float* dinvc= (float*)alloc(N * 4);
    float* invc = (float*)alloc(N * 4);
    float* psrc = (float*)alloc(N * 4);
    float* pdst = (float*)alloc(N * 4);
    float* csum = (float*)alloc(256 * 4);
    float* csq  = (float*)alloc(256 * 4);
    float* mu   = (float*)alloc(256 * 4);
    float* rstd = (float*)alloc(256 * 4);
    int* cnt    = (int*)alloc(N * 4);
    int* cursor = (int*)alloc(N * 4);
    int* roff   = (int*)alloc((N + 1) * 4);
    int* csrc   = (int*)alloc((size_t)E * 4);
    unsigned short* Ah = (unsigned short*)alloc((size_t)N * DIM * 2);
    unsigned short* Al = (unsigned short*)alloc((size_t)N * DIM * 2);
    unsigned short* Bh = (unsigned short*)alloc((size_t)NPAD * DIM * 2);
    unsigned short* Bl = (unsigned short*)alloc((size_t)NPAD * DIM * 2);

    const int EB = (E + 255) / 256;
    dim3 blk256(256);

    // ---- graph prep ----
    hipMemsetAsync(cnt, 0, (size_t)N * 4, stream);
    hipMemsetAsync(cursor, 0, (size_t)N * 4, stream);
    k_hist<<<EB, blk256, 0, stream>>>(dst, cnt, E);
    k_scan4096<<<1, 1024, 0, stream>>>(cnt, roff);
    k_csr_fill<<<EB, blk256, 0, stream>>>(src, dst, roff, cursor, csrc, E);
    k_coefs<<<(N + 255) / 256, blk256, 0, stream>>>(cnt, dinv, dinvc, invc, N);

    // ---- prediction weight conversion (depends only on pw; do it early) ----
    k_convB<<<dim3(NPAD / 64, DIM / 64), blk256, 0, stream>>>(pw, Bh, Bl, DIM, NC);

    // ---- embed + MLP ----
    k_embed<<<N, 128, 0, stream>>>(ui, ii, eu, ei, x0);
    gemm64<1,1,0><<<dim3(HID1/64, N/64), blk256, 0, stream>>>(x0, w1, b1, h1, N, 128, HID1);
    gemm64<1,1,0><<<dim3(HID2/64, N/64), blk256, 0, stream>>>(h1, w2, b2, h2, N, HID1, HID2);

    // ---- GCN layer 0 ----
    gemm64<0,0,0><<<dim3(DIM/64, N/64), blk256, 0, stream>>>(h2, gw0, nullptr, xb, N, HID2, DIM);
    k_gcn_agg<<<N, blk256, 0, stream>>>(xb, roff, csrc, dinv, gb0, xc);
    hipMemsetAsync(csum, 0, 256 * 4, stream);
    hipMemsetAsync(csq, 0, 256 * 4, stream);
    k_colstats<<<N / 64, blk256, 0, stream>>>(xc, csum, csq);
    k_bnfin<<<1, 256, 0, stream>>>(csum, csq, mu, rstd, 1.0f / (float)N);
    k_bnapply<<<N, blk256, 0, stream>>>(xc, mu, rstd, bg0, bb0, xa);

    // ---- GCN layer 1 ----
    gemm64<0,0,0><<<dim3(DIM/64, N/64), blk256, 0, stream>>>(xa, gw1, nullptr, xb, N, DIM, DIM);
    k_gcn_agg<<<N, blk256, 0, stream>>>(xb, roff, csrc, dinv, gb1, xc);
    hipMemsetAsync(csum, 0, 256 * 4, stream);
    hipMemsetAsync(csq, 0, 256 * 4, stream);
    k_colstats<<<N / 64, blk256, 0, stream>>>(xc, csum, csq);
    k_bnfin<<<1, 256, 0, stream>>>(csum, csq, mu, rstd, 1.0f / (float)N);
    k_bnapply<<<N, blk256, 0, stream>>>(xc, mu, rstd, bg1, bb1, xa);

    // ---- SAGE: x = relu(mean_nbr@wl + bl + x@wr) ----
    k_sage_agg<<<N, blk256, 0, stream>>>(xa, roff, csrc, invc, xd);
    gemm64<0,0,0><<<dim3(DIM/64, N/64), blk256, 0, stream>>>(xa, swr, nullptr, xb, N, DIM, DIM);
    gemm64<1,1,1><<<dim3(DIM/64, N/64), blk256, 0, stream>>>(xd, swl, sbl, xb, N, DIM, DIM);

    // ---- Cheb: x = relu(x@w0 + tx1@w1 + b) ----
    k_cheb_agg<<<N, blk256, 0, stream>>>(xb, roff, csrc, dinvc, xd);
    gemm64<0,0,0><<<dim3(DIM/64, N/64), blk256, 0, stream>>>(xb, cw0, nullptr, xc, N, DIM, DIM);
    gemm64<1,1,1><<<dim3(DIM/64, N/64), blk256, 0, stream>>>(xd, cw1, cb, xc, N, DIM, DIM);

    // ---- GAT layer 0 ----
    gemm64<0,0,0><<<dim3(DIM/64, N/64), blk256, 0, stream>>>(xc, aw0, nullptr, xb, N, DIM, DIM);
    k_gat_proj<<<N, blk256, 0, stream>>>(xb, as0, ad0, psrc, pdst);
    k_gat_agg<<<N, blk256, 0, stream>>>(xb, psrc, pdst, roff, csrc, ab0, xa);

    // ---- GAT layer 1 ----
    gemm64<0,0,0><<<dim3(DIM/64, N/64), blk256, 0, stream>>>(xa, aw1, nullptr, xb, N, DIM, DIM);
    k_gat_proj<<<N, blk256, 0, stream>>>(xb, as1, ad1, psrc, pdst);
    k_gat_agg<<<N, blk256, 0, stream>>>(xb, psrc, pdst, roff, csrc, ab1, xc);

    // ---- prediction: out = xc @ pw + pb  (split-bf16 MFMA, 3 terms) ----
    k_convA<<<(N * DIM + 255) / 256, blk256, 0, stream>>>(xc, Ah, Al, N * DIM);
    gemm_pred_mfma<<<dim3(NPAD / 128, N / 128), blk256, 0, stream>>>(Ah, Al, Bh, Bl, pb, out, NC);
}

// Round 5
// 1586.737 us; speedup vs baseline: 1.0250x; 1.0250x over previous
//
#include <hip/hip_runtime.h>
#include <hip/hip_bf16.h>
#include <math.h>

// ---------------- constants for this problem ----------------
#define DIM 256       // graph-layer width
#define EMB 64
#define HID1 1024
#define HID2 512
#define EPSBN 1e-5f

typedef float f32x4 __attribute__((ext_vector_type(4)));
typedef __bf16 bf16x8 __attribute__((ext_vector_type(8)));

// ---------------- bf16 split helpers ----------------
__device__ __forceinline__ unsigned short f2bf(float f) {
    unsigned u = __float_as_uint(f);
    unsigned r = (u + 0x7fffu + ((u >> 16) & 1u)) >> 16;
    return (unsigned short)r;
}
__device__ __forceinline__ float bf2f(unsigned short h) {
    return __uint_as_float(((unsigned)h) << 16);
}

// ---------------- small utility kernels ----------------

__global__ __launch_bounds__(128) void k_embed(const int* __restrict__ ui, const int* __restrict__ ii,
                                               const float* __restrict__ eu, const float* __restrict__ ei,
                                               float* __restrict__ x0) {
    int i = blockIdx.x, t = threadIdx.x;
    float v = (t < 64) ? eu[(size_t)ui[i] * 64 + t] : ei[(size_t)ii[i] * 64 + (t - 64)];
    x0[(size_t)i * 128 + t] = v;
}

__global__ __launch_bounds__(256) void k_hist(const int* __restrict__ dst, int* __restrict__ cnt, int E) {
    int e = blockIdx.x * 256 + threadIdx.x;
    if (e < E) atomicAdd(&cnt[dst[e]], 1);
}

// exclusive scan of 4096 ints (single block, 1024 threads x 4)
__global__ __launch_bounds__(1024) void k_scan4096(const int* __restrict__ cnt, int* __restrict__ roff) {
    __shared__ int s[1024];
    int t = threadIdx.x;
    int v0 = cnt[4*t], v1 = cnt[4*t+1], v2 = cnt[4*t+2], v3 = cnt[4*t+3];
    int loc = v0 + v1 + v2 + v3;
    s[t] = loc;
    for (int o = 1; o < 1024; o <<= 1) {
        __syncthreads();
        int x = (t >= o) ? s[t - o] : 0;
        __syncthreads();
        s[t] += x;
    }
    __syncthreads();
    int excl = s[t] - loc;
    roff[4*t]   = excl;
    roff[4*t+1] = excl + v0;
    roff[4*t+2] = excl + v0 + v1;
    roff[4*t+3] = excl + v0 + v1 + v2;
    if (t == 1023) roff[4096] = s[1023];
}

__global__ __launch_bounds__(256) void k_csr_fill(const int* __restrict__ src, const int* __restrict__ dst,
                                                  const int* __restrict__ roff, int* __restrict__ cursor,
                                                  int* __restrict__ csrc, int E) {
    int e = blockIdx.x * 256 + threadIdx.x;
    if (e < E) {
        int d = dst[e];
        int pos = roff[d] + atomicAdd(&cursor[d], 1);
        csrc[pos] = src[e];
    }
}

__global__ __launch_bounds__(256) void k_coefs(const int* __restrict__ cnt, float* __restrict__ dinv,
                                               float* __restrict__ dinvc, float* __restrict__ invc, int n) {
    int i = blockIdx.x * 256 + threadIdx.x;
    if (i < n) {
        int c = cnt[i];
        dinv[i]  = rsqrtf((float)c + 1.0f);
        dinvc[i] = (c > 0) ? rsqrtf((float)c) : 0.0f;
        invc[i]  = 1.0f / (float)(c > 0 ? c : 1);
    }
}

// ---------------- fp32 tiled GEMM: C[M,N] = A[M,K] @ B[K,N] ----------------
// 64x64 block tile, 4x4 per thread, BK=32. M%64==0, K%32==0 assumed. N guarded.
template<int BIAS, int RELU, int ACC>
__global__ __launch_bounds__(256) void gemm64(const float* __restrict__ A, const float* __restrict__ B,
                                              const float* __restrict__ bias, float* __restrict__ C,
                                              int M, int K, int N) {
    __shared__ float As[32][68];   // [k][m]
    __shared__ float Bs[32][68];   // [k][n]
    const int bn = blockIdx.x * 64, bm = blockIdx.y * 64;
    const int tid = threadIdx.x;
    const int tx = tid & 15, ty = tid >> 4;
    const int alm = tid >> 2;           // 0..63  A row within tile
    const int alk = (tid & 3) * 8;      // 0,8,16,24
    const int blk = tid >> 3;           // 0..31 B row (k)
    const int bln = (tid & 7) * 8;      // 0..56
    const bool nfull = (bn + 64 <= N);

    float acc[4][4] = {};

    for (int k0 = 0; k0 < K; k0 += 32) {
        const float* ap = A + (size_t)(bm + alm) * K + k0 + alk;
        float4 a0 = *(const float4*)ap;
        float4 a1 = *(const float4*)(ap + 4);
        As[alk+0][alm] = a0.x; As[alk+1][alm] = a0.y; As[alk+2][alm] = a0.z; As[alk+3][alm] = a0.w;
        As[alk+4][alm] = a1.x; As[alk+5][alm] = a1.y; As[alk+6][alm] = a1.z; As[alk+7][alm] = a1.w;

        const float* bp = B + (size_t)(k0 + blk) * N + bn + bln;
        if (nfull) {
            *(float4*)&Bs[blk][bln]     = *(const float4*)bp;
            *(float4*)&Bs[blk][bln + 4] = *(const float4*)(bp + 4);
        } else {
            #pragma unroll
            for (int j = 0; j < 8; ++j)
                Bs[blk][bln + j] = (bn + bln + j < N) ? bp[j] : 0.0f;
        }
        __syncthreads();
        #pragma unroll
        for (int k = 0; k < 32; ++k) {
            float4 av = *(const float4*)&As[k][ty * 4];
            float4 bv = *(const float4*)&Bs[k][tx * 4];
            float a[4] = {av.x, av.y, av.z, av.w};
            float b[4] = {bv.x, bv.y, bv.z, bv.w};
            #pragma unroll
            for (int i = 0; i < 4; ++i)
                #pragma unroll
                for (int j = 0; j < 4; ++j)
                    acc[i][j] = fmaf(a[i], b[j], acc[i][j]);
        }
        __syncthreads();
    }

    const int row = bm + ty * 4, col = bn + tx * 4;
    #pragma unroll
    for (int i = 0; i < 4; ++i) {
        float* cp = C + (size_t)(row + i) * N + col;
        #pragma unroll
        for (int j = 0; j < 4; ++j) {
            if (col + j < N) {
                float v = acc[i][j];
                if (ACC)  v += cp[j];
                if (BIAS) v += bias[col + j];
                if (RELU) v = fmaxf(v, 0.0f);
                cp[j] = v;
            }
        }
    }
}

// ---------------- split-bf16 conversion kernels ----------------

// X [total] f32 -> Ah, Al bf16 (hi + residual)
__global__ __launch_bounds__(256) void k_convA(const float* __restrict__ X, unsigned short* __restrict__ Ah,
                                               unsigned short* __restrict__ Al, int total) {
    int i = blockIdx.x * 256 + threadIdx.x;
    if (i < total) {
        float f = X[i];
        unsigned short h = f2bf(f);
        Ah[i] = h;
        Al[i] = f2bf(f - bf2f(h));
    }
}

// W [K=256][NC] f32 row-major  ->  Bh, Bl [NPAD][256] bf16 (transposed + split), pad rows zeroed.
// grid (NPAD/64, K/64), 256 threads; tile 64k x 64n via LDS.
__global__ __launch_bounds__(256) void k_convB(const float* __restrict__ W, unsigned short* __restrict__ Bh,
                                               unsigned short* __restrict__ Bl, int K, int NC) {
    __shared__ float tile[64][65];
    const int n0 = blockIdx.x * 64, k0 = blockIdx.y * 64;
    const int t = threadIdx.x;
    const int tn = t & 63, tk4 = t >> 6;
    for (int kk = tk4; kk < 64; kk += 4) {
        int n = n0 + tn;
        tile[kk][tn] = (n < NC) ? W[(size_t)(k0 + kk) * NC + n] : 0.0f;
    }
    __syncthreads();
    const int wn = t >> 2, wk = (t & 3) * 16;
    size_t base = (size_t)(n0 + wn) * K + k0 + wk;
    #pragma unroll
    for (int j = 0; j < 16; ++j) {
        float f = tile[wk + j][wn];
        unsigned short h = f2bf(f);
        Bh[base + j] = h;
        Bl[base + j] = f2bf(f - bf2f(h));
    }
}

// ---------------- split-bf16 MFMA prediction GEMM ----------------
// C[4096, NC] = (Ah+Al)[4096,256] @ (Bh+Bl) + bias, via Ah*Bh + Ah*Bl + Al*Bh.
// A*: [4096][256] bf16 row-major. B*: [NPAD][256] bf16 (n-major, pre-transposed).
// 128x128 tile, 4 waves (2x2), BK=64, 16x16x32 bf16 MFMA.
//   * stage all 4 tiles (Ah,Al,Bh,Bl) ONCE per K-step, run 3 terms against them
//     -> per-block staging 384 KB -> 256 KB, MFMA:ds_read 3:1 (was 2:1)
//   * grid dims swapped: blockIdx.x = M-tile (fast), blockIdx.y = N-tile.
//     bid = bx + 32*by, 32%8==0 -> each XCD permanently owns 4 A-panels
//     (512 KB L2-resident); B tiles fetched ~once per XCD per column.
// LDS XOR swizzle (slot ^= row&7) on global source + ds_read side (rule #21).
__global__ __launch_bounds__(256) void gemm_pred_mfma(
    const unsigned short* __restrict__ Ah, const unsigned short* __restrict__ Al,
    const unsigned short* __restrict__ Bh, const unsigned short* __restrict__ Bl,
    const float* __restrict__ bias, float* __restrict__ C, int NC) {
    __shared__ char lds[65536];            // 4 x 16 KB tiles
    char* AhS = lds;
    char* AlS = lds + 16384;
    char* BhS = lds + 32768;
    char* BlS = lds + 49152;
    const int tid = threadIdx.x;
    const int w = tid >> 6, l = tid & 63;
    const int wr = w >> 1, wc = w & 1;            // wave 64x64 sub-tile
    const int g = l >> 4, lr = l & 15;
    const int bm = blockIdx.x * 128, bn = blockIdx.y * 128;   // M fast, N slow

    f32x4 acc[4][4] = {};

    for (int kk = 0; kk < 256; kk += 64) {
        // stage: each wave fills 32 rows of each of the 4 tiles (8 rows/1KB per call)
        #pragma unroll
        for (int c = 0; c < 4; ++c) {
            const int row = w * 32 + c * 8 + (l >> 3);   // tile-local row
            const int q = l & 7;                         // linear LDS slot this lane fills
            const int gs = q ^ (row & 7);                // pre-swizzled global slot
            const size_t goffA = (size_t)(bm + row) * 256 + kk + gs * 8;
            const size_t goffB = (size_t)(bn + row) * 256 + kk + gs * 8;
            const int ldsoff = (w * 32 + c * 8) * 128;
            __builtin_amdgcn_global_load_lds(
                (const __attribute__((address_space(1))) void*)(Ah + goffA),
                (__attribute__((address_space(3))) void*)(AhS + ldsoff), 16, 0, 0);
            __builtin_amdgcn_global_load_lds(
                (const __attribute__((address_space(1))) void*)(Al + goffA),
                (__attribute__((address_space(3))) void*)(AlS + ldsoff), 16, 0, 0);
            __builtin_amdgcn_global_load_lds(
                (const __attribute__((address_space(1))) void*)(Bh + goffB),
                (__attribute__((address_space(3))) void*)(BhS + ldsoff), 16, 0, 0);
            __builtin_amdgcn_global_load_lds(
                (const __attribute__((address_space(1))) void*)(Bl + goffB),
                (__attribute__((address_space(3))) void*)(BlS + ldsoff), 16, 0, 0);
        }
        __syncthreads();
        #pragma unroll
        for (int ks = 0; ks < 2; ++ks) {          // two k-slices of 32
            bf16x8 ah[4], al[4], bh[4], bl[4];
            #pragma unroll
            for (int m = 0; m < 4; ++m) {
                const int row = wr * 64 + m * 16 + lr;
                const int slot = (ks * 4 + g) ^ (row & 7);
                ah[m] = *(const bf16x8*)(AhS + row * 128 + slot * 16);
                al[m] = *(const bf16x8*)(AlS + row * 128 + slot * 16);
            }
            #pragma unroll
            for (int n = 0; n < 4; ++n) {
                const int row = wc * 64 + n * 16 + lr;
                const int slot = (ks * 4 + g) ^ (row & 7);
                bh[n] = *(const bf16x8*)(BhS + row * 128 + slot * 16);
                bl[n] = *(const bf16x8*)(BlS + row * 128 + slot * 16);
            }
            #pragma unroll
            for (int m = 0; m < 4; ++m)
                #pragma unroll
                for (int n = 0; n < 4; ++n) {
                    acc[m][n] = __builtin_amdgcn_mfma_f32_16x16x32_bf16(ah[m], bh[n], acc[m][n], 0, 0, 0);
                    acc[m][n] = __builtin_amdgcn_mfma_f32_16x16x32_bf16(ah[m], bl[n], acc[m][n], 0, 0, 0);
                    acc[m][n] = __builtin_amdgcn_mfma_f32_16x16x32_bf16(al[m], bh[n], acc[m][n], 0, 0, 0);
                }
        }
        __syncthreads();
    }
    // epilogue: C/D mapping col=lane&15, row=(lane>>4)*4+reg  [m89-verified]
    #pragma unroll
    for (int n = 0; n < 4; ++n) {
        const int col = bn + wc * 64 + n * 16 + lr;
        if (col < NC) {
            const float bv = bias[col];
            #pragma unroll
            for (int m = 0; m < 4; ++m) {
                const int row0 = bm + wr * 64 + m * 16 + g * 4;
                #pragma unroll
                for (int r = 0; r < 4; ++r)
                    C[(size_t)(row0 + r) * NC + col] = acc[m][n][r] + bv;
            }
        }
    }
}

// ---------------- aggregations (block per node, 256 threads = 256 cols) ----------------

__global__ __launch_bounds__(256) void k_gcn_agg(const float* __restrict__ xw, const int* __restrict__ roff,
                                                 const int* __restrict__ csrc, const float* __restrict__ dinv,
                                                 const float* __restrict__ b, float* __restrict__ out) {
    int i = blockIdx.x, c = threadIdx.x;
    float di = dinv[i];
    float acc = xw[(size_t)i * DIM + c] * di * di;
    int beg = roff[i], end = roff[i + 1];
    for (int j = beg; j < end; ++j) {
        int s = csrc[j];
        acc = fmaf(xw[(size_t)s * DIM + c], dinv[s] * di, acc);
    }
    out[(size_t)i * DIM + c] = acc + b[c];
}

__global__ __launch_bounds__(256) void k_sage_agg(const float* __restrict__ x, const int* __restrict__ roff,
                                                  const int* __restrict__ csrc, const float* __restrict__ invc,
                                                  float* __restrict__ out) {
    int i = blockIdx.x, c = threadIdx.x;
    float acc = 0.0f;
    int beg = roff[i], end = roff[i + 1];
    for (int j = beg; j < end; ++j) acc += x[(size_t)csrc[j] * DIM + c];
    out[(size_t)i * DIM + c] = acc * invc[i];
}

__global__ __launch_bounds__(256) void k_cheb_agg(const float* __restrict__ x, const int* __restrict__ roff,
                                                  const int* __restrict__ csrc, const float* __restrict__ dinvc,
                                                  float* __restrict__ out) {
    int i = blockIdx.x, c = threadIdx.x;
    float dci = dinvc[i];
    float acc = 0.0f;
    int beg = roff[i], end = roff[i + 1];
    for (int j = beg; j < end; ++j) {
        int s = csrc[j];
        acc = fmaf(x[(size_t)s * DIM + c], -(dinvc[s] * dci), acc);
    }
    out[(size_t)i * DIM + c] = acc;
}

// ---------------- BatchNorm (batch stats) ----------------

__global__ __launch_bounds__(256) void k_colstats(const float* __restrict__ X, float* __restrict__ sum,
                                                  float* __restrict__ sq) {
    int c = threadIdx.x;
    int r0 = blockIdx.x * 64;
    float s = 0.0f, q = 0.0f;
    for (int r = r0; r < r0 + 64; ++r) {
        float v = X[(size_t)r * DIM + c];
        s += v;
        q = fmaf(v, v, q);
    }
    atomicAdd(&sum[c], s);
    atomicAdd(&sq[c], q);
}

__global__ __launch_bounds__(256) void k_bnfin(const float* __restrict__ sum, const float* __restrict__ sq,
                                               float* __restrict__ mu, float* __restrict__ rstd, float invn) {
    int c = threadIdx.x;
    float m = sum[c] * invn;
    float var = sq[c] * invn - m * m;
    mu[c] = m;
    rstd[c] = rsqrtf(var + EPSBN);
}

__global__ __launch_bounds__(256) void k_bnapply(const float* __restrict__ X, const float* __restrict__ mu,
                                                 const float* __restrict__ rstd, const float* __restrict__ g,
                                                 const float* __restrict__ bt, float* __restrict__ out) {
    int r = blockIdx.x, c = threadIdx.x;
    size_t idx = (size_t)r * DIM + c;
    float v = (X[idx] - mu[c]) * rstd[c] * g[c] + bt[c];
    out[idx] = fmaxf(v, 0.0f);
}

// ---------------- GAT ----------------

__global__ __launch_bounds__(256) void k_gat_proj(const float* __restrict__ xw, const float* __restrict__ a_s,
                                                  const float* __restrict__ a_d, float* __restrict__ ps,
                                                  float* __restrict__ pd) {
    int i = blockIdx.x, t = threadIdx.x;
    __shared__ float r1[256], r2[256];
    float v = xw[(size_t)i * DIM + t];
    r1[t] = v * a_s[t];
    r2[t] = v * a_d[t];
    __syncthreads();
    for (int o = 128; o > 0; o >>= 1) {
        if (t < o) { r1[t] += r1[t + o]; r2[t] += r2[t + o]; }
        __syncthreads();
    }
    if (t == 0) { ps[i] = r1[0]; pd[i] = r2[0]; }
}

__device__ __forceinline__ float leaky02(float x) { return x > 0.0f ? x : 0.2f * x; }

__global__ __launch_bounds__(256) void k_gat_agg(const float* __restrict__ xw, const float* __restrict__ ps,
                                                 const float* __restrict__ pd, const int* __restrict__ roff,
                                                 const int* __restrict__ csrc, const float* __restrict__ b,
                                                 float* __restrict__ out) {
    int i = blockIdx.x, t = threadIdx.x;
    int beg = roff[i], end = roff[i + 1];
    float ad = pd[i];
    __shared__ float red[256];
    // pass 1: segment max (edges + self loop)
    float lm = -1e30f;
    for (int j = beg + t; j < end; j += 256) lm = fmaxf(lm, leaky02(ps[csrc[j]] + ad));
    if (t == 0) lm = fmaxf(lm, leaky02(ps[i] + ad));
    red[t] = lm; __syncthreads();
    for (int o = 128; o > 0; o >>= 1) { if (t < o) red[t] = fmaxf(red[t], red[t + o]); __syncthreads(); }
    float m = red[0]; __syncthreads();
    // pass 2: sum of exp
    float ls = 0.0f;
    for (int j = beg + t; j < end; j += 256) ls += __expf(leaky02(ps[csrc[j]] + ad) - m);
    if (t == 0) ls += __expf(leaky02(ps[i] + ad) - m);
    red[t] = ls; __syncthreads();
    for (int o = 128; o > 0; o >>= 1) { if (t < o) red[t] += red[t + o]; __syncthreads(); }
    float inv_s = 1.0f / red[0];
    // pass 3: weighted aggregate (t = column)
    float acc = __expf(leaky02(ps[i] + ad) - m) * xw[(size_t)i * DIM + t];
    for (int j = beg; j < end; ++j) {
        int s = csrc[j];
        acc = fmaf(__expf(leaky02(ps[s] + ad) - m), xw[(size_t)s * DIM + t], acc);
    }
    float v = acc * inv_s + b[t];
    out[(size_t)i * DIM + t] = v > 0.0f ? v : expm1f(v);
}

// ---------------- host-side launch ----------------

extern "C" void kernel_launch(void* const* d_in, const int* in_sizes, int n_in,
                              void* d_out, int out_size, void* d_ws, size_t ws_size,
                              hipStream_t stream) {
    const int*   ui  = (const int*)d_in[0];
    const int*   ii  = (const int*)d_in[1];
    const int*   edg = (const int*)d_in[2];
    const float* eu  = (const float*)d_in[3];
    const float* ei  = (const float*)d_in[4];
    const float* w1  = (const float*)d_in[5];  const float* b1  = (const float*)d_in[6];
    const float* w2  = (const float*)d_in[7];  const float* b2  = (const float*)d_in[8];
    const float* gw0 = (const float*)d_in[9];  const float* gb0 = (const float*)d_in[10];
    const float* bg0 = (const float*)d_in[11]; const float* bb0 = (const float*)d_in[12];
    const float* gw1 = (const float*)d_in[13]; const float* gb1 = (const float*)d_in[14];
    const float* bg1 = (const float*)d_in[15]; const float* bb1 = (const float*)d_in[16];
    const float* swl = (const float*)d_in[17]; const float* sbl = (const float*)d_in[18];
    const float* swr = (const float*)d_in[19];
    const float* cw0 = (const float*)d_in[20]; const float* cw1 = (const float*)d_in[21];
    const float* cb  = (const float*)d_in[22];
    const float* aw0 = (const float*)d_in[23]; const float* as0 = (const float*)d_in[24];
    const float* ad0 = (const float*)d_in[25]; const float* ab0 = (const float*)d_in[26];
    const float* aw1 = (const float*)d_in[27]; const float* as1 = (const float*)d_in[28];
    const float* ad1 = (const float*)d_in[29]; const float* ab1 = (const float*)d_in[30];
    const float* pw  = (const float*)d_in[31]; const float* pb  = (const float*)d_in[32];
    float* out = (float*)d_out;

    const int N  = in_sizes[0];          // 4096
    const int E  = in_sizes[2] / 2;      // 131072
    const int NC = in_sizes[32];         // 41476
    const int NPAD = ((NC + 127) / 128) * 128;   // 41600
    const int* src = edg;
    const int* dst = edg + E;

    // workspace carve (256B aligned chunks)
    char* p = (char*)d_ws;
    auto alloc = [&](size_t bytes) -> void* {
        void* r = (void*)p;
        p += ((bytes + 255) / 256) * 256;
        return r;
    };
    float* x0   = (float*)alloc((size_t)N * 128 * 4);
    float* h1   = (float*)alloc((size_t)N * HID1 * 4);
    float* h2   = (float*)alloc((size_t)N * HID2 * 4);
    float* xa   = (float*)alloc((size_t)N * DIM * 4);
    float* xb   = (float*)alloc((size_t)N * DIM * 4);
    float* xc   = (float*)alloc((size_t)N * DIM * 4);
    float* xd   = (float*)alloc((size_t)N * DIM * 4);
    float* dinv = (float*)alloc(N * 4);
    float* dinvc= (float*)alloc(N * 4);
    float* invc = (float*)alloc(N * 4);
    float* psrc = (float*)alloc(N * 4);
    float* pdst = (float*)alloc(N * 4);
    float* csum = (float*)alloc(256 * 4);
    float* csq  = (float*)alloc(256 * 4);
    float* mu   = (float*)alloc(256 * 4);
    float* rstd = (float*)alloc(256 * 4);
    int* cnt    = (int*)alloc(N * 4);
    int* cursor = (int*)alloc(N * 4);
    int* roff   = (int*)alloc((N + 1) * 4);
    int* csrc   = (int*)alloc((size_t)E * 4);
    unsigned short* Ah = (unsigned short*)alloc((size_t)N * DIM * 2);
    unsigned short* Al = (unsigned short*)alloc((size_t)N * DIM * 2);
    unsigned short* Bh = (unsigned short*)alloc((size_t)NPAD * DIM * 2);
    unsigned short* Bl = (unsigned short*)alloc((size_t)NPAD * DIM * 2);

    const int EB = (E + 255) / 256;
    dim3 blk256(256);

    // ---- graph prep ----
    hipMemsetAsync(cnt, 0, (size_t)N * 4, stream);
    hipMemsetAsync(cursor, 0, (size_t)N * 4, stream);
    k_hist<<<EB, blk256, 0, stream>>>(dst, cnt, E);
    k_scan4096<<<1, 1024, 0, stream>>>(cnt, roff);
    k_csr_fill<<<EB, blk256, 0, stream>>>(src, dst, roff, cursor, csrc, E);
    k_coefs<<<(N + 255) / 256, blk256, 0, stream>>>(cnt, dinv, dinvc, invc, N);

    // ---- prediction weight conversion (depends only on pw; do it early) ----
    k_convB<<<dim3(NPAD / 64, DIM / 64), blk256, 0, stream>>>(pw, Bh, Bl, DIM, NC);

    // ---- embed + MLP ----
    k_embed<<<N, 128, 0, stream>>>(ui, ii, eu, ei, x0);
    gemm64<1,1,0><<<dim3(HID1/64, N/64), blk256, 0, stream>>>(x0, w1, b1, h1, N, 128, HID1);
    gemm64<1,1,0><<<dim3(HID2/64, N/64), blk256, 0, stream>>>(h1, w2, b2, h2, N, HID1, HID2);

    // ---- GCN layer 0 ----
    gemm64<0,0,0><<<dim3(DIM/64, N/64), blk256, 0, stream>>>(h2, gw0, nullptr, xb, N, HID2, DIM);
    k_gcn_agg<<<N, blk256, 0, stream>>>(xb, roff, csrc, dinv, gb0, xc);
    hipMemsetAsync(csum, 0, 256 * 4, stream);
    hipMemsetAsync(csq, 0, 256 * 4, stream);
    k_colstats<<<N / 64, blk256, 0, stream>>>(xc, csum, csq);
    k_bnfin<<<1, 256, 0, stream>>>(csum, csq, mu, rstd, 1.0f / (float)N);
    k_bnapply<<<N, blk256, 0, stream>>>(xc, mu, rstd, bg0, bb0, xa);

    // ---- GCN layer 1 ----
    gemm64<0,0,0><<<dim3(DIM/64, N/64), blk256, 0, stream>>>(xa, gw1, nullptr, xb, N, DIM, DIM);
    k_gcn_agg<<<N, blk256, 0, stream>>>(xb, roff, csrc, dinv, gb1, xc);
    hipMemsetAsync(csum, 0, 256 * 4, stream);
    hipMemsetAsync(csq, 0, 256 * 4, stream);
    k_colstats<<<N / 64, blk256, 0, stream>>>(xc, csum, csq);
    k_bnfin<<<1, 256, 0, stream>>>(csum, csq, mu, rstd, 1.0f / (float)N);
    k_bnapply<<<N, blk256, 0, stream>>>(xc, mu, rstd, bg1, bb1, xa);

    // ---- SAGE: x = relu(mean_nbr@wl + bl + x@wr) ----
    k_sage_agg<<<N, blk256, 0, stream>>>(xa, roff, csrc, invc, xd);
    gemm64<0,0,0><<<dim3(DIM/64, N/64), blk256, 0, stream>>>(xa, swr, nullptr, xb, N, DIM, DIM);
    gemm64<1,1,1><<<dim3(DIM/64, N/64), blk256, 0, stream>>>(xd, swl, sbl, xb, N, DIM, DIM);

    // ---- Cheb: x = relu(x@w0 + tx1@w1 + b) ----
    k_cheb_agg<<<N, blk256, 0, stream>>>(xb, roff, csrc, dinvc, xd);
    gemm64<0,0,0><<<dim3(DIM/64, N/64), blk256, 0, stream>>>(xb, cw0, nullptr, xc, N, DIM, DIM);
    gemm64<1,1,1><<<dim3(DIM/64, N/64), blk256, 0, stream>>>(xd, cw1, cb, xc, N, DIM, DIM);

    // ---- GAT layer 0 ----
    gemm64<0,0,0><<<dim3(DIM/64, N/64), blk256, 0, stream>>>(xc, aw0, nullptr, xb, N, DIM, DIM);
    k_gat_proj<<<N, blk256, 0, stream>>>(xb, as0, ad0, psrc, pdst);
    k_gat_agg<<<N, blk256, 0, stream>>>(xb, psrc, pdst, roff, csrc, ab0, xa);

    // ---- GAT layer 1 ----
    gemm64<0,0,0><<<dim3(DIM/64, N/64), blk256, 0, stream>>>(xa, aw1, nullptr, xb, N, DIM, DIM);
    k_gat_proj<<<N, blk256, 0, stream>>>(xb, as1, ad1, psrc, pdst);
    k_gat_agg<<<N, blk256, 0, stream>>>(xb, psrc, pdst, roff, csrc, ab1, xc);

    // ---- prediction: out = xc @ pw + pb  (split-bf16 MFMA, 3 terms, M-fast grid) ----
    k_convA<<<(N * DIM + 255) / 256, blk256, 0, stream>>>(xc, Ah, Al, N * DIM);
    gemm_pred_mfma<<<dim3(N / 128, NPAD / 128), blk256, 0, stream>>>(Ah, Al, Bh, Bl, pb, out, NC);
}